// Round 10
// baseline (29657.715 us; speedup 1.0000x reference)
//
#include <hip/hip_runtime.h>
#include <math.h>

#define TT 200
#define NDIM 1024
#define IDIM 128
#define ODIM 128
#define NB 256

// ws float offsets
#define JT_OFF 0          // f32 Jt[k][n] = J[n][k]           (1024x1024)
#define BT_OFF 1048576    // f32 Bt[i][n] = B[n][i]           (128x1024)
#define W4_OFF 1179648    // f32 W4[kq][o][4] = W[o][4kq+kk]  (1024x128)
#define SG_OFF 1310720    // f32 Sg[2][256][1024] sigmoid(V)
#define TH_OFF 1835008    // f32 Th[2][256][1024] tanh(V)
#define BAR_OFF 2359296   // u32 cnt[16] @ +0, u32 flg[16] @ +64 (u32 index)

// d_out float offsets
#define VT_STRIDE 205824
#define ZT_BASE   52690944
#define OUTS_BASE 105381888

__global__ __launch_bounds__(256) void rsnn_prologue(
    const float* __restrict__ J, const float* __restrict__ Bm,
    const float* __restrict__ W, float* __restrict__ ws,
    float* __restrict__ out) {
  const int blk = blockIdx.x, tid = threadIdx.x;
  __shared__ float tile[32][33];
  if (blk < 1024) {
    int tk = blk >> 5, tn = blk & 31;
    int k0 = tk * 32, n0 = tn * 32;
    int c = tid & 31, r0 = tid >> 5;
#pragma unroll
    for (int j = 0; j < 4; ++j) {
      int r = r0 + j * 8;
      tile[r][c] = J[(n0 + r) * NDIM + (k0 + c)];
    }
    __syncthreads();
#pragma unroll
    for (int j = 0; j < 4; ++j) {
      int r = r0 + j * 8;
      ws[JT_OFF + (k0 + r) * NDIM + (n0 + c)] = tile[c][r];
    }
  } else if (blk < 1152) {
    const int i = blk - 1024;
    const int n = tid << 2;
    float4 v;
    v.x = Bm[(size_t)(n + 0) * IDIM + i];
    v.y = Bm[(size_t)(n + 1) * IDIM + i];
    v.z = Bm[(size_t)(n + 2) * IDIM + i];
    v.w = Bm[(size_t)(n + 3) * IDIM + i];
    *(float4*)(ws + BT_OFF + (size_t)i * NDIM + n) = v;
  } else if (blk < 1280) {
    const int o = blk - 1152;
    float4 v = *(const float4*)(W + (size_t)o * NDIM + (tid << 2));
    *(float4*)(ws + W4_OFF + (size_t)tid * 512 + (o << 2)) = v;
  } else {
    const int idx = (blk - 1280) * 256 + tid;
    ws[SG_OFF + idx] = 0.5f;
    ws[TH_OFF + idx] = 0.0f;
    const int b = idx >> 10, n = idx & 1023;
    out[(size_t)b * VT_STRIDE + n] = 0.0f;
    out[ZT_BASE + (size_t)b * VT_STRIDE + n] = 0.0f;
    if (idx < 128) ((unsigned*)(ws + BAR_OFF))[idx] = 0u;
  }
}

__global__ __launch_bounds__(256, 1) void rsnn_persist(
    const float* __restrict__ inputs, const float* __restrict__ noise,
    float* __restrict__ ws, float* __restrict__ out) {
  const int tid = threadIdx.x;
  const int l = tid & 63;
  const int q = __builtin_amdgcn_readfirstlane(tid >> 6);
  const int bt = blockIdx.x >> 4, nt = blockIdx.x & 15;
  const int b0 = bt << 4;
  const int n = (nt << 6) + l;

  const float* JT = ws + JT_OFF;
  const float* BT = ws + BT_OFF;
  const float* W4 = ws + W4_OFF;
  float* Sg = ws + SG_OFF;
  float* Th = ws + TH_OFF;
  unsigned* cnt = (unsigned*)(ws + BAR_OFF) + bt;
  unsigned* flg = (unsigned*)(ws + BAR_OFF) + 64 + bt;

  __shared__ float red[4][16][64];
  __shared__ float red2[4][128];

  float jr[288];
  const int kb = q * 288;
  if (q < 3) {
#pragma unroll
    for (int k = 0; k < 288; ++k) jr[k] = JT[(size_t)(kb + k) * NDIM + n];
  } else {
#pragma unroll
    for (int k = 0; k < 160; ++k) jr[k] = JT[(size_t)(864 + k) * NDIM + n];
#pragma unroll
    for (int i = 0; i < 128; ++i) jr[160 + i] = BT[(size_t)i * NDIM + n];
  }

  float vreg[4] = {0.f, 0.f, 0.f, 0.f};

  for (int s = 0; s <= TT; ++s) {
    if (s) {
      __syncthreads();
      if (tid == 0) {
        __threadfence();
        unsigned prev = __hip_atomic_fetch_add(cnt, 1u, __ATOMIC_RELAXED,
                                               __HIP_MEMORY_SCOPE_AGENT);
        if (prev == 15u) {
          __hip_atomic_store(cnt, 0u, __ATOMIC_RELAXED, __HIP_MEMORY_SCOPE_AGENT);
          __hip_atomic_store(flg, (unsigned)s, __ATOMIC_RELEASE,
                             __HIP_MEMORY_SCOPE_AGENT);
        } else {
          while (__hip_atomic_load(flg, __ATOMIC_RELAXED,
                                   __HIP_MEMORY_SCOPE_AGENT) < (unsigned)s)
            __builtin_amdgcn_s_sleep(1);
        }
        __threadfence();
      }
      __syncthreads();
    }

    if (s < TT) {
      const float* Sp = Sg + (size_t)(s & 1) * (NB * NDIM);
      if (q < 3) {
#pragma unroll 1
        for (int bp = 0; bp < 8; ++bp) {
          const float* SA = Sp + (size_t)(b0 + 2 * bp) * NDIM + kb;
          const float* SB = SA + NDIM;
          float a0 = 0.f, a1 = 0.f;
#pragma unroll
          for (int g = 0; g < 72; ++g) {
            const float4 sa = *(const float4*)(SA + (g << 2));
            const float4 sb = *(const float4*)(SB + (g << 2));
            a0 = fmaf(sa.x, jr[(g << 2) + 0], a0);
            a0 = fmaf(sa.y, jr[(g << 2) + 1], a0);
            a0 = fmaf(sa.z, jr[(g << 2) + 2], a0);
            a0 = fmaf(sa.w, jr[(g << 2) + 3], a0);
            a1 = fmaf(sb.x, jr[(g << 2) + 0], a1);
            a1 = fmaf(sb.y, jr[(g << 2) + 1], a1);
            a1 = fmaf(sb.z, jr[(g << 2) + 2], a1);
            a1 = fmaf(sb.w, jr[(g << 2) + 3], a1);
          }
          red[q][2 * bp][l] = a0;
          red[q][2 * bp + 1][l] = a1;
        }
      } else {
#pragma unroll 1
        for (int bp = 0; bp < 8; ++bp) {
          const int bA = b0 + 2 * bp;
          const float* SA = Sp + (size_t)bA * NDIM + 864;
          const float* SB = SA + NDIM;
          float a0 = 0.f, a1 = 0.f;
#pragma unroll
          for (int g = 0; g < 40; ++g) {
            const float4 sa = *(const float4*)(SA + (g << 2));
            const float4 sb = *(const float4*)(SB + (g << 2));
            a0 = fmaf(sa.x, jr[(g << 2) + 0], a0);
            a0 = fmaf(sa.y, jr[(g << 2) + 1], a0);
            a0 = fmaf(sa.z, jr[(g << 2) + 2], a0);
            a0 = fmaf(sa.w, jr[(g << 2) + 3], a0);
            a1 = fmaf(sb.x, jr[(g << 2) + 0], a1);
            a1 = fmaf(sb.y, jr[(g << 2) + 1], a1);
            a1 = fmaf(sb.z, jr[(g << 2) + 2], a1);
            a1 = fmaf(sb.w, jr[(g << 2) + 3], a1);
          }
          const float* XA = inputs + ((size_t)bA * TT + s) * IDIM;
          const float* XB = inputs + ((size_t)(bA + 1) * TT + s) * IDIM;
#pragma unroll
          for (int g = 0; g < 32; ++g) {
            const float4 xa = *(const float4*)(XA + (g << 2));
            const float4 xb = *(const float4*)(XB + (g << 2));
            a0 = fmaf(xa.x, jr[160 + (g << 2) + 0], a0);
            a0 = fmaf(xa.y, jr[160 + (g << 2) + 1], a0);
            a0 = fmaf(xa.z, jr[160 + (g << 2) + 2], a0);
            a0 = fmaf(xa.w, jr[160 + (g << 2) + 3], a0);
            a1 = fmaf(xb.x, jr[160 + (g << 2) + 0], a1);
            a1 = fmaf(xb.y, jr[160 + (g << 2) + 1], a1);
            a1 = fmaf(xb.z, jr[160 + (g << 2) + 2], a1);
            a1 = fmaf(xb.w, jr[160 + (g << 2) + 3], a1);
          }
          red[3][2 * bp][l] = a0;
          red[3][2 * bp + 1][l] = a1;
        }
      }
    }

    if (s >= 1) {
      const float* Tp = Th + (size_t)(s & 1) * (NB * NDIM);
#pragma unroll
      for (int r = 0; r < 2; ++r) {
        const int bq = (r << 3) + (l >> 3);
        const int o = (nt << 3) + (l & 7);
        const float* trow = Tp + (size_t)(b0 + bq) * NDIM;
        float acco = 0.f;
        const int k0 = q << 8;
#pragma unroll 8
        for (int k = k0; k < k0 + 256; k += 4) {
          float4 tq = *(const float4*)(trow + k);
          float4 wq = *(const float4*)(W4 + (size_t)(k >> 2) * 512 + (o << 2));
          acco = fmaf(tq.x, wq.x, acco);
          acco = fmaf(tq.y, wq.y, acco);
          acco = fmaf(tq.z, wq.z, acco);
          acco = fmaf(tq.w, wq.w, acco);
        }
        red2[q][(r << 6) + l] = acco;
      }
    }
    __syncthreads();

    if (s < TT) {
      const int p = (s + 1) & 1;
      float* Sgn = Sg + (size_t)p * (NB * NDIM);
      float* Thn = Th + (size_t)p * (NB * NDIM);
#pragma unroll
      for (int e = 0; e < 4; ++e) {
        const int idx = (e << 8) + tid;
        const int i = idx >> 6, nc = idx & 63;
        float sum = ((red[0][i][nc] + red[1][i][nc]) + red[2][i][nc]) +
                    red[3][i][nc];
        const int b = b0 + i;
        const int ng = (nt << 6) + nc;
        float vnew = 0.9f * vreg[e] + 0.1f * sum;
        vreg[e] = vnew;
        out[(size_t)b * VT_STRIDE + (size_t)(s + 1) * NDIM + ng] = vnew;
        float sg = 1.0f / (1.0f + expf(-vnew));
        Sgn[(size_t)b * NDIM + ng] = sg;
        Thn[(size_t)b * NDIM + ng] = tanhf(vnew);
        float zarg = (0.1f * (vnew - 0.4f)) / 0.4f;
        float zs = 1.0f / (1.0f + expf(-zarg));
        float u = noise[((size_t)b * TT + s) * NDIM + ng];
        out[ZT_BASE + (size_t)b * VT_STRIDE + (size_t)(s + 1) * NDIM + ng] =
            (zs > u) ? 1.0f : 0.0f;
      }
    }

    if (s >= 1 && tid < 128) {
      float sum2 = ((red2[0][tid] + red2[1][tid]) + red2[2][tid]) + red2[3][tid];
      const int b2 = tid >> 3, oo = tid & 7;
      out[OUTS_BASE + ((size_t)(b0 + b2) * TT + (s - 1)) * ODIM + (nt << 3) + oo] =
          sum2;
    }
  }
}

extern "C" void kernel_launch(void* const* d_in, const int* in_sizes, int n_in,
                              void* d_out, int out_size, void* d_ws, size_t ws_size,
                              hipStream_t stream) {
  const float* inputs = (const float*)d_in[0];  // (256,200,128)
  const float* noise  = (const float*)d_in[1];  // (256,200,1024)
  const float* J      = (const float*)d_in[2];  // (1024,1024)
  const float* Bm     = (const float*)d_in[3];  // (1024,128)
  const float* W      = (const float*)d_in[4];  // (128,1024)
  float* out = (float*)d_out;
  float* ws  = (float*)d_ws;

  rsnn_prologue<<<2304, 256, 0, stream>>>(J, Bm, W, ws, out);
  rsnn_persist<<<256, 256, 0, stream>>>(inputs, noise, ws, out);
}

// Round 12
// 14094.371 us; speedup vs baseline: 2.1042x; 2.1042x over previous
//
#include <hip/hip_runtime.h>
#include <math.h>

#define TT 200
#define NDIM 1024
#define IDIM 128
#define ODIM 128
#define NB 256

// ws float offsets (state only; J/B/W used from natural inputs)
#define SG_OFF 0          // f32 Sg[2][256][1024] sigmoid(V)
#define TH_OFF 524288     // f32 Th[2][256][1024] tanh(V)
#define BAR_OFF 1048576   // u32 cnt[8] @ +0, u32 flg[8] @ +16 (u32 index)

// d_out float offsets
#define VT_STRIDE 205824
#define ZT_BASE   52690944
#define OUTS_BASE 105381888

#define JSTR 1028   // 4KB row + 16B pad: 16B-aligned rows, even bank spread
#define BSTR 132

__global__ __launch_bounds__(256) void rsnn_prologue(float* __restrict__ ws,
                                                     float* __restrict__ out) {
  const int idx = blockIdx.x * 256 + threadIdx.x;   // 0..262143
  ws[SG_OFF + idx] = 0.5f;                          // sigmoid(0), parity 0
  ws[TH_OFF + idx] = 0.0f;                          // tanh(0),   parity 0
  const int b = idx >> 10, n = idx & 1023;
  out[(size_t)b * VT_STRIDE + n] = 0.0f;
  out[ZT_BASE + (size_t)b * VT_STRIDE + n] = 0.0f;
  // R11 BUG FIX: flg lives at u32 indices 16..23; idx<16 left it 0xAA-poisoned
  // -> every spin fell through -> no inter-block sync -> racy zt flips.
  if (idx < 32) ((unsigned*)(ws + BAR_OFF))[idx] = 0u;
}

// Persistent: 256 blocks (g=blk>>5: 32-batch group, nt=blk&31: 32-neuron tile)
// x 512 threads. J-slice (32 rows) + B-slice live in LDS for all 200 steps.
// Each thread owns 2 cells (bA,n),(bA+16,n) with FULL k -> R1's exact chains
// {0-287,288-575,576-863,864-1023+input}, reduce ((p0+p1)+p2)+p3, verbatim
// epilogue => bit-identical v/z. Per-group barrier = 32 blocks (R8 protocol).
// outs (not bit-critical): o-slice 4 per block, W streamed, 4-way k-split.
__global__ __launch_bounds__(512, 1) void rsnn_persist(
    const float* __restrict__ inputs, const float* __restrict__ noise,
    const float* __restrict__ J, const float* __restrict__ Bm,
    const float* __restrict__ W,
    float* __restrict__ ws, float* __restrict__ out) {
  const int tid = threadIdx.x;
  const int g = blockIdx.x >> 5;        // 0..7 batch-group
  const int nt = blockIdx.x & 31;       // 0..31 neuron tile
  const int bbase = g << 5;
  const int n0 = nt << 5;

  float* Sg = ws + SG_OFF;
  float* Th = ws + TH_OFF;
  unsigned* cnt = (unsigned*)(ws + BAR_OFF) + g;
  unsigned* flg = (unsigned*)(ws + BAR_OFF) + 16 + g;

  __shared__ float J_lds[32 * JSTR];    // 131.6 KB
  __shared__ float B_lds[32 * BSTR];    // 16.9 KB
  __shared__ float red2[4][32][4];      // 2 KB

  // one-time: stage J rows [n0,n0+32) and B rows into LDS (coalesced)
  {
    const int r = tid >> 4;             // 0..31
    const int c0 = (tid & 15) << 6;     // 0,64,...,960
    const float* src = J + (size_t)(n0 + r) * NDIM + c0;
    float* dst = J_lds + r * JSTR + c0;
#pragma unroll
    for (int j = 0; j < 16; ++j)
      *(float4*)(dst + (j << 2)) = *(const float4*)(src + (j << 2));
    if ((tid & 15) < 2) {
      const int i0 = (tid & 15) << 6;
      const float* bsrc = Bm + (size_t)(n0 + r) * IDIM + i0;
      float* bdst = B_lds + r * BSTR + i0;
#pragma unroll
      for (int j = 0; j < 16; ++j)
        *(float4*)(bdst + (j << 2)) = *(const float4*)(bsrc + (j << 2));
    }
  }
  __syncthreads();

  const int n_l = tid & 31;
  const int bh = tid >> 5;              // 0..15
  const int bA = bbase + bh, bB = bA + 16;
  const int ng = n0 + n_l;
  const float* Jrow = J_lds + n_l * JSTR;
  const float* Brow = B_lds + n_l * BSTR;

  float vA = 0.f, vB = 0.f;

  for (int s = 0; s <= TT; ++s) {
    if (s) {
      // ---- per-group barrier (32 blocks), R8/R9/R10-proven protocol ----
      __syncthreads();
      if (tid == 0) {
        __threadfence();
        unsigned prev = __hip_atomic_fetch_add(cnt, 1u, __ATOMIC_RELAXED,
                                               __HIP_MEMORY_SCOPE_AGENT);
        if (prev == 31u) {
          __hip_atomic_store(cnt, 0u, __ATOMIC_RELAXED, __HIP_MEMORY_SCOPE_AGENT);
          __hip_atomic_store(flg, (unsigned)s, __ATOMIC_RELEASE,
                             __HIP_MEMORY_SCOPE_AGENT);
        } else {
          while (__hip_atomic_load(flg, __ATOMIC_RELAXED,
                                   __HIP_MEMORY_SCOPE_AGENT) < (unsigned)s)
            __builtin_amdgcn_s_sleep(1);
        }
        __threadfence();
      }
      __syncthreads();
    }

    if (s < TT) {
      const float* Sp = Sg + (size_t)(s & 1) * (NB * NDIM);
      const float* SA = Sp + (size_t)bA * NDIM;
      const float* SB = Sp + (size_t)bB * NDIM;
      float pA[4], pB[4];
#pragma unroll
      for (int q = 0; q < 3; ++q) {     // full unroll: static pA/pB indices
        float aA = 0.f, aB = 0.f;
        const int kb = q * 288;
#pragma unroll 8
        for (int g4 = 0; g4 < 72; ++g4) {
          const int k = kb + (g4 << 2);
          const float4 sa = *(const float4*)(SA + k);
          const float4 sb = *(const float4*)(SB + k);
          const float4 jv = *(const float4*)(Jrow + k);
          aA = fmaf(sa.x, jv.x, aA); aA = fmaf(sa.y, jv.y, aA);
          aA = fmaf(sa.z, jv.z, aA); aA = fmaf(sa.w, jv.w, aA);
          aB = fmaf(sb.x, jv.x, aB); aB = fmaf(sb.y, jv.y, aB);
          aB = fmaf(sb.z, jv.z, aB); aB = fmaf(sb.w, jv.w, aB);
        }
        pA[q] = aA; pB[q] = aB;
      }
      {
        float aA = 0.f, aB = 0.f;
#pragma unroll 8
        for (int g4 = 0; g4 < 40; ++g4) {   // k = 864..1023
          const int k = 864 + (g4 << 2);
          const float4 sa = *(const float4*)(SA + k);
          const float4 sb = *(const float4*)(SB + k);
          const float4 jv = *(const float4*)(Jrow + k);
          aA = fmaf(sa.x, jv.x, aA); aA = fmaf(sa.y, jv.y, aA);
          aA = fmaf(sa.z, jv.z, aA); aA = fmaf(sa.w, jv.w, aA);
          aB = fmaf(sb.x, jv.x, aB); aB = fmaf(sb.y, jv.y, aB);
          aB = fmaf(sb.z, jv.z, aB); aB = fmaf(sb.w, jv.w, aB);
        }
        const float* XA = inputs + ((size_t)bA * TT + s) * IDIM;
        const float* XB = inputs + ((size_t)bB * TT + s) * IDIM;
#pragma unroll 8
        for (int i4 = 0; i4 < 32; ++i4) {   // input proj appended (R1 order)
          const int i = i4 << 2;
          const float4 xa = *(const float4*)(XA + i);
          const float4 xb = *(const float4*)(XB + i);
          const float4 bv = *(const float4*)(Brow + i);
          aA = fmaf(xa.x, bv.x, aA); aA = fmaf(xa.y, bv.y, aA);
          aA = fmaf(xa.z, bv.z, aA); aA = fmaf(xa.w, bv.w, aA);
          aB = fmaf(xb.x, bv.x, aB); aB = fmaf(xb.y, bv.y, aB);
          aB = fmaf(xb.z, bv.z, aB); aB = fmaf(xb.w, bv.w, aB);
        }
        pA[3] = aA; pB[3] = aB;
      }
      const float sumA = ((pA[0] + pA[1]) + pA[2]) + pA[3];
      const float sumB = ((pB[0] + pB[1]) + pB[2]) + pB[3];

      const int p = (s + 1) & 1;
      float* Sgn = Sg + (size_t)p * (NB * NDIM);
      float* Thn = Th + (size_t)p * (NB * NDIM);
      // cell A epilogue (verbatim R1)
      {
        float vnew = 0.9f * vA + 0.1f * sumA;
        vA = vnew;
        out[(size_t)bA * VT_STRIDE + (size_t)(s + 1) * NDIM + ng] = vnew;
        float sgv = 1.0f / (1.0f + expf(-vnew));
        Sgn[(size_t)bA * NDIM + ng] = sgv;
        Thn[(size_t)bA * NDIM + ng] = tanhf(vnew);
        float zarg = (0.1f * (vnew - 0.4f)) / 0.4f;
        float zs = 1.0f / (1.0f + expf(-zarg));
        float u = noise[((size_t)bA * TT + s) * NDIM + ng];
        out[ZT_BASE + (size_t)bA * VT_STRIDE + (size_t)(s + 1) * NDIM + ng] =
            (zs > u) ? 1.0f : 0.0f;
      }
      // cell B epilogue
      {
        float vnew = 0.9f * vB + 0.1f * sumB;
        vB = vnew;
        out[(size_t)bB * VT_STRIDE + (size_t)(s + 1) * NDIM + ng] = vnew;
        float sgv = 1.0f / (1.0f + expf(-vnew));
        Sgn[(size_t)bB * NDIM + ng] = sgv;
        Thn[(size_t)bB * NDIM + ng] = tanhf(vnew);
        float zarg = (0.1f * (vnew - 0.4f)) / 0.4f;
        float zs = 1.0f / (1.0f + expf(-zarg));
        float u = noise[((size_t)bB * TT + s) * NDIM + ng];
        out[ZT_BASE + (size_t)bB * VT_STRIDE + (size_t)(s + 1) * NDIM + ng] =
            (zs > u) ? 1.0f : 0.0f;
      }
    }

    if (s >= 1) {
      // ---- outs partials for t = s-1: (kq, b_l, o_l) = (tid>>7, .., tid&3)
      const float* Tp = Th + (size_t)(s & 1) * (NB * NDIM);
      const int kq = tid >> 7, rem = tid & 127;
      const int b_l = rem >> 2, o_l = rem & 3;
      const int ob = bbase + b_l;
      const int o = (nt << 2) + o_l;
      const float* trow = Tp + (size_t)ob * NDIM + (kq << 8);
      const float* wrow = W + (size_t)o * NDIM + (kq << 8);
      float acc = 0.f;
#pragma unroll 8
      for (int k4 = 0; k4 < 64; ++k4) {
        const float4 t = *(const float4*)(trow + (k4 << 2));
        const float4 wv = *(const float4*)(wrow + (k4 << 2));
        acc = fmaf(t.x, wv.x, acc);
        acc = fmaf(t.y, wv.y, acc);
        acc = fmaf(t.z, wv.z, acc);
        acc = fmaf(t.w, wv.w, acc);
      }
      red2[kq][b_l][o_l] = acc;
    }
    __syncthreads();
    if (s >= 1 && tid < 128) {
      const int b_l = tid >> 2, o_l = tid & 3;
      float sum2 = ((red2[0][b_l][o_l] + red2[1][b_l][o_l]) +
                    red2[2][b_l][o_l]) + red2[3][b_l][o_l];
      const int ob = bbase + b_l;
      const int o = (nt << 2) + o_l;
      out[OUTS_BASE + ((size_t)ob * TT + (s - 1)) * ODIM + o] = sum2;
    }
  }
}

extern "C" void kernel_launch(void* const* d_in, const int* in_sizes, int n_in,
                              void* d_out, int out_size, void* d_ws, size_t ws_size,
                              hipStream_t stream) {
  const float* inputs = (const float*)d_in[0];  // (256,200,128)
  const float* noise  = (const float*)d_in[1];  // (256,200,1024)
  const float* J      = (const float*)d_in[2];  // (1024,1024)
  const float* Bm     = (const float*)d_in[3];  // (1024,128)
  const float* W      = (const float*)d_in[4];  // (128,1024)
  float* out = (float*)d_out;
  float* ws  = (float*)d_ws;

  rsnn_prologue<<<1024, 256, 0, stream>>>(ws, out);
  rsnn_persist<<<256, 512, 0, stream>>>(inputs, noise, J, Bm, W, ws, out);
}